// Round 1
// baseline (390.817 us; speedup 1.0000x reference)
//
#include <hip/hip_runtime.h>

using bf16x8 = __attribute__((ext_vector_type(8))) short;
using f32x4  = __attribute__((ext_vector_type(4))) float;

#define MFMA(a,b,c) __builtin_amdgcn_mfma_f32_16x16x32_bf16((a),(b),(c),0,0,0)

__device__ __forceinline__ short f2bf(float f) {
  unsigned u = __builtin_bit_cast(unsigned, f);
  u += 0x7FFFu + ((u >> 16) & 1u);   // RNE
  return (short)(u >> 16);
}
__device__ __forceinline__ float sigm(float x) { return 1.0f / (1.0f + __expf(-x)); }
__device__ __forceinline__ float tanh_(float x) { return 2.0f * sigm(2.0f * x) - 1.0f; }

__device__ __forceinline__ bf16x8 pack8(float4 a, float4 b) {
  bf16x8 r;
  r[0]=f2bf(a.x); r[1]=f2bf(a.y); r[2]=f2bf(a.z); r[3]=f2bf(a.w);
  r[4]=f2bf(b.x); r[5]=f2bf(b.y); r[6]=f2bf(b.z); r[7]=f2bf(b.w);
  return r;
}

// ---------------- prep: weights -> bf16, im2col-friendly layouts ----------------
__global__ void k_prep(const float* __restrict__ w1, const float* __restrict__ w2,
                       const float* __restrict__ w3, const float* __restrict__ wih,
                       const float* __restrict__ whh, const float* __restrict__ aw,
                       const float* __restrict__ lw,
                       short* __restrict__ w1p, short* __restrict__ w2p, short* __restrict__ w3p,
                       short* __restrict__ wihp, short* __restrict__ whhp,
                       short* __restrict__ attnp, short* __restrict__ linp)
{
  int i = blockIdx.x * 256 + threadIdx.x;
  if (i < 8192) {                       // w1p [128][64], k=c*9+dy*3+dx, pad 36..63 = 0
    int o = i >> 6, k = i & 63;
    float v = 0.f;
    if (k < 36) { int c = k / 9, r9 = k % 9; v = w1[((o*4 + c)*3 + r9/3)*3 + (r9%3)]; }
    w1p[i] = f2bf(v); return;
  }
  i -= 8192;
  if (i < 32768) {                      // w2p [64][512], k=(dy*2+dx)*128+c
    int o = i >> 9, k = i & 511;
    int dydx = k >> 7, c = k & 127;
    w2p[i] = f2bf(w2[((o*128 + c)*2 + (dydx>>1))*2 + (dydx&1)]); return;
  }
  i -= 32768;
  if (i < 16384) {                      // w3p [64][256], k=(dy*2+dx)*64+c
    int o = i >> 8, k = i & 255;
    int dydx = k >> 6, c = k & 63;
    w3p[i] = f2bf(w3[((o*64 + c)*2 + (dydx>>1))*2 + (dydx&1)]); return;
  }
  i -= 16384;
  if (i < 24576) { wihp[i] = f2bf(wih[i]); return; }
  i -= 24576;
  if (i < 196608) { whhp[i] = f2bf(whh[i]); return; }
  i -= 196608;
  if (i < 16384) { attnp[i] = f2bf(aw[i]); return; }
  i -= 16384;
  if (i < 589824) { linp[i] = f2bf(lw[i]); return; }
}

// ---------------- GRU (fused emb gather + gi + gh + gates) + attn ----------------
// 128 blocks x 512 thr. Btile=32 samples/block. Wave w owns hidden cols [32w,32w+32).
__global__ __launch_bounds__(512, 1) void k_gru(
    const int* __restrict__ inst, const float* __restrict__ emb_w,
    const short* __restrict__ wihp, const short* __restrict__ whhp,
    const float* __restrict__ b_ih, const float* __restrict__ b_hh,
    const short* __restrict__ attnp, const float* __restrict__ attn_b,
    float* __restrict__ attn_out)
{
  __shared__ short hL[32 * 256];     // bf16 h, XOR-swizzled (row stride 512B)
  const int tid = threadIdx.x;
  const int w = tid >> 6, l = tid & 63, lr = l & 15, lk = l >> 4;
  const int b0 = blockIdx.x * 32;
  const f32x4 z4 = {0.f, 0.f, 0.f, 0.f};

  for (int i = tid; i < 32 * 256; i += 512) hL[i] = 0;

  // nt 0..1 = r, 2..3 = z, 4..5 = n ; each covers 16 cols
  int rowW[6];
  #pragma unroll
  for (int nt = 0; nt < 6; ++nt) rowW[nt] = (nt >> 1) * 256 + w * 32 + (nt & 1) * 16 + lr;

  bf16x8 wih[6];
  #pragma unroll
  for (int nt = 0; nt < 6; ++nt) wih[nt] = *(const bf16x8*)(wihp + rowW[nt] * 32 + lk * 8);

  float biasRZ[4], bihN[2], bhhN[2];
  #pragma unroll
  for (int nt = 0; nt < 4; ++nt) biasRZ[nt] = b_ih[rowW[nt]] + b_hh[rowW[nt]];
  #pragma unroll
  for (int s = 0; s < 2; ++s) { bihN[s] = b_ih[rowW[4 + s]]; bhhN[s] = b_hh[rowW[4 + s]]; }

  float hOld[2][2][4];
  #pragma unroll
  for (int mi = 0; mi < 2; ++mi)
    #pragma unroll
    for (int s = 0; s < 2; ++s)
      #pragma unroll
      for (int e = 0; e < 4; ++e) hOld[mi][s][e] = 0.f;

  __syncthreads();

  for (int t = 0; t < 16; ++t) {
    bf16x8 xf[2];
    #pragma unroll
    for (int mi = 0; mi < 2; ++mi) {
      int bb = b0 + mi * 16 + lr;
      int id = inst[bb * 16 + t];
      const float* ep = emb_w + id * 32 + lk * 8;
      xf[mi] = pack8(*(const float4*)(ep), *(const float4*)(ep + 4));
    }
    f32x4 acc[2][6], gin[2][2];
    #pragma unroll
    for (int mi = 0; mi < 2; ++mi) {
      #pragma unroll
      for (int nt = 0; nt < 4; ++nt) acc[mi][nt] = MFMA(xf[mi], wih[nt], z4);
      #pragma unroll
      for (int s = 0; s < 2; ++s) gin[mi][s] = MFMA(xf[mi], wih[4 + s], z4);
      acc[mi][4] = z4; acc[mi][5] = z4;
    }
    #pragma unroll
    for (int ks = 0; ks < 8; ++ks) {
      bf16x8 hf[2];
      #pragma unroll
      for (int mi = 0; mi < 2; ++mi) {
        int row = mi * 16 + lr;
        int byte = (row * 512 + ks * 64 + lk * 16) ^ ((row & 7) << 4);
        hf[mi] = *(const bf16x8*)((const char*)hL + byte);
      }
      #pragma unroll
      for (int nt = 0; nt < 6; ++nt) {
        bf16x8 bw = *(const bf16x8*)(whhp + rowW[nt] * 256 + ks * 32 + lk * 8);
        acc[0][nt] = MFMA(hf[0], bw, acc[0][nt]);
        acc[1][nt] = MFMA(hf[1], bw, acc[1][nt]);
      }
    }
    __syncthreads();   // all reads of h(t-1) done before overwriting
    #pragma unroll
    for (int mi = 0; mi < 2; ++mi)
      #pragma unroll
      for (int s = 0; s < 2; ++s)
        #pragma unroll
        for (int e = 0; e < 4; ++e) {
          float r  = sigm(acc[mi][s][e]     + biasRZ[s]);
          float zz = sigm(acc[mi][2 + s][e] + biasRZ[2 + s]);
          float nn = tanh_(gin[mi][s][e] + bihN[s] + r * (acc[mi][4 + s][e] + bhhN[s]));
          float hn = (1.0f - zz) * nn + zz * hOld[mi][s][e];
          hOld[mi][s][e] = hn;
          int row = mi * 16 + lk * 4 + e;          // D layout: row=(lane>>4)*4+reg
          int col = w * 32 + s * 16 + lr;          // D layout: col=lane&15
          int byte = (row * 512 + col * 2) ^ ((row & 7) << 4);
          *(short*)((char*)hL + byte) = f2bf(hn);
        }
    __syncthreads();
  }

  // attn = sigmoid(h @ attn_w^T + attn_b): wave -> (mi = w>>2, nt = w&3)
  {
    const int mi = w >> 2, nt = w & 3;
    f32x4 acc = z4;
    #pragma unroll
    for (int ks = 0; ks < 8; ++ks) {
      int row = mi * 16 + lr;
      int byte = (row * 512 + ks * 64 + lk * 16) ^ ((row & 7) << 4);
      bf16x8 hf = *(const bf16x8*)((const char*)hL + byte);
      bf16x8 bw = *(const bf16x8*)(attnp + (nt * 16 + lr) * 256 + ks * 32 + lk * 8);
      acc = MFMA(hf, bw, acc);
    }
    float bb = attn_b[nt * 16 + lr];
    #pragma unroll
    for (int e = 0; e < 4; ++e) {
      int row = mi * 16 + lk * 4 + e;
      attn_out[(b0 + row) * 64 + nt * 16 + lr] = sigm(acc[e] + bb);
    }
  }
}

// ---------------- fused conv1+conv2+conv3 + gating + PE -> flat bf16 ----------------
// 1 sample per block, 256 thr (4 waves).
__global__ __launch_bounds__(256, 4) void k_conv(
    const float* __restrict__ x,
    const short* __restrict__ w1p, const float* __restrict__ b1,
    const short* __restrict__ w2p, const float* __restrict__ b2,
    const short* __restrict__ w3p, const float* __restrict__ b3,
    const float* __restrict__ attn, const int* __restrict__ steps,
    short* __restrict__ flat)
{
  __shared__ float xs[400];
  __shared__ short A1[64 * 64];    // im2col conv1, K padded to 64, swizzled (row 128B)
  __shared__ short a1[64 * 128];   // conv1 out NHWC bf16, swizzled (row 256B)
  __shared__ short a2[49 * 64];    // conv2 out NHWC bf16, swizzled (row 128B)
  __shared__ short fst[2304];      // flat staging

  const int tid = threadIdx.x;
  const int w = tid >> 6, l = tid & 63, lr = l & 15, lk = l >> 4;
  const int b = blockIdx.x;
  const f32x4 z4 = {0.f, 0.f, 0.f, 0.f};

  for (int i = tid; i < 400; i += 256) xs[i] = x[b * 400 + i];
  __syncthreads();

  for (int i = tid; i < 4096; i += 256) {     // build im2col A1
    int p = i >> 6, k = i & 63;
    float v = 0.f;
    if (k < 36) {
      int c = k / 9, r9 = k % 9;
      v = xs[c * 100 + ((p >> 3) + r9 / 3) * 10 + (p & 7) + (r9 % 3)];
    }
    int byte = (p * 128 + k * 2) ^ ((p & 7) << 4);
    *(short*)((char*)A1 + byte) = f2bf(v);
  }
  __syncthreads();

  // conv1: wave w -> oc tiles {2w,2w+1} (base w*32); M=64 pixels, K=64(pad)
  f32x4 acc1[4][2];
  #pragma unroll
  for (int m = 0; m < 4; ++m) { acc1[m][0] = z4; acc1[m][1] = z4; }
  {
    bf16x8 wf[2][2];
    #pragma unroll
    for (int n = 0; n < 2; ++n)
      #pragma unroll
      for (int ks = 0; ks < 2; ++ks)
        wf[n][ks] = *(const bf16x8*)(w1p + (w * 32 + n * 16 + lr) * 64 + ks * 32 + lk * 8);
    #pragma unroll
    for (int ks = 0; ks < 2; ++ks)
      #pragma unroll
      for (int m = 0; m < 4; ++m) {
        int row = m * 16 + lr;
        int byte = (row * 128 + ks * 64 + lk * 16) ^ ((row & 7) << 4);
        bf16x8 af = *(const bf16x8*)((const char*)A1 + byte);
        acc1[m][0] = MFMA(af, wf[0][ks], acc1[m][0]);
        acc1[m][1] = MFMA(af, wf[1][ks], acc1[m][1]);
      }
  }
  #pragma unroll
  for (int m = 0; m < 4; ++m)
    #pragma unroll
    for (int n = 0; n < 2; ++n) {
      int oc = w * 32 + n * 16 + lr;
      float bb = b1[oc];
      #pragma unroll
      for (int e = 0; e < 4; ++e) {
        int p = m * 16 + lk * 4 + e;
        float v = fmaxf(acc1[m][n][e] + bb, 0.f);
        int byte = (p * 256 + oc * 2) ^ ((p & 7) << 4);
        *(short*)((char*)a1 + byte) = f2bf(v);
      }
    }
  __syncthreads();

  // conv2: wave w -> oc tile w*16; M=49(pad 64), K=512, A read straight from a1
  f32x4 acc2[4];
  #pragma unroll
  for (int m = 0; m < 4; ++m) acc2[m] = z4;
  {
    int base2[4];
    #pragma unroll
    for (int m = 0; m < 4; ++m) {
      int p = m * 16 + lr; if (p > 48) p = 48;
      base2[m] = (p / 7) * 8 + p % 7;
    }
    const int off2[4] = {0, 1, 8, 9};
    #pragma unroll
    for (int ks = 0; ks < 16; ++ks) {
      bf16x8 bf = *(const bf16x8*)(w2p + (w * 16 + lr) * 512 + ks * 32 + lk * 8);
      int dydx = ks >> 2;
      int colb = (ks & 3) * 64 + lk * 16;
      #pragma unroll
      for (int m = 0; m < 4; ++m) {
        int row = base2[m] + off2[dydx];
        int byte = (row * 256 + colb) ^ ((row & 7) << 4);
        bf16x8 af = *(const bf16x8*)((const char*)a1 + byte);
        acc2[m] = MFMA(af, bf, acc2[m]);
      }
    }
  }
  {
    int oc = w * 16 + lr;
    float bb = b2[oc];
    #pragma unroll
    for (int m = 0; m < 4; ++m)
      #pragma unroll
      for (int e = 0; e < 4; ++e) {
        int p = m * 16 + lk * 4 + e;
        if (p < 49) {
          float v = fmaxf(acc2[m][e] + bb, 0.f);
          int byte = (p * 128 + oc * 2) ^ ((p & 7) << 4);
          *(short*)((char*)a2 + byte) = f2bf(v);
        }
      }
  }
  __syncthreads();

  // conv3: M=36(pad 48), K=256
  f32x4 acc3[3];
  #pragma unroll
  for (int m = 0; m < 3; ++m) acc3[m] = z4;
  {
    int base3[3];
    #pragma unroll
    for (int m = 0; m < 3; ++m) {
      int p = m * 16 + lr; if (p > 35) p = 35;
      base3[m] = (p / 6) * 7 + p % 6;
    }
    const int off3[4] = {0, 1, 7, 8};
    #pragma unroll
    for (int ks = 0; ks < 8; ++ks) {
      bf16x8 bf = *(const bf16x8*)(w3p + (w * 16 + lr) * 256 + ks * 32 + lk * 8);
      int dydx = ks >> 1;
      int colb = (ks & 1) * 64 + lk * 16;
      #pragma unroll
      for (int m = 0; m < 3; ++m) {
        int row = base3[m] + off3[dydx];
        int byte = (row * 128 + colb) ^ ((row & 7) << 4);
        bf16x8 af = *(const bf16x8*)((const char*)a2 + byte);
        acc3[m] = MFMA(af, bf, acc3[m]);
      }
    }
  }
  // epilogue: bias+relu, * attn[b][oc], + PE[steps[b]][oc*36+p], -> fst bf16
  {
    int oc = w * 16 + lr;
    float av = attn[b * 64 + oc];
    float bb = b3[oc];
    float sf = (float)steps[b];
    const float C = (float)(-2.0 * (9.210340371976184 / 2304.0));  // -2*ln(1e4)/2304
    #pragma unroll
    for (int m = 0; m < 3; ++m)
      #pragma unroll
      for (int e = 0; e < 4; ++e) {
        int p = m * 16 + lk * 4 + e;
        if (p < 36) {
          float v = fmaxf(acc3[m][e] + bb, 0.f) * av;
          int k = oc * 36 + p;
          float ang = sf * expf((float)(k >> 1) * C);
          float pe = (k & 1) ? cosf(ang) : sinf(ang);
          fst[k] = f2bf(v + pe);
        }
      }
  }
  __syncthreads();
  for (int i = tid; i < 288; i += 256)
    *(bf16x8*)(flat + b * 2304 + i * 8) = *(const bf16x8*)(fst + i * 8);
}

// ---------------- lin (M=4096,N=256,K=2304) + relu + critic ----------------
// 256 blocks (BM=16, BN=256 full), 256 thr (4 waves, wave w -> cols [64w,64w+64))
__global__ __launch_bounds__(256, 4) void k_lin(
    const short* __restrict__ flat, const short* __restrict__ linp,
    const float* __restrict__ lin_b, const float* __restrict__ crit_w,
    const float* __restrict__ crit_b, float* __restrict__ out)
{
  __shared__ float hidL[16 * 260];   // +4 pad: breaks 1KB-stride bank aliasing
  __shared__ float cw[1024];
  const int tid = threadIdx.x;
  const int w = tid >> 6, l = tid & 63, lr = l & 15, lk = l >> 4;
  const int m0 = blockIdx.x * 16;
  const f32x4 z4 = {0.f, 0.f, 0.f, 0.f};

  for (int i = tid; i < 1024; i += 256) cw[i] = crit_w[i];

  f32x4 acc[4];
  #pragma unroll
  for (int nt = 0; nt < 4; ++nt) acc[nt] = z4;

  #pragma unroll 2
  for (int ks = 0; ks < 72; ++ks) {
    bf16x8 af = *(const bf16x8*)(flat + (m0 + lr) * 2304 + ks * 32 + lk * 8);
    #pragma unroll
    for (int nt = 0; nt < 4; ++nt) {
      bf16x8 bf = *(const bf16x8*)(linp + (w * 64 + nt * 16 + lr) * 2304 + ks * 32 + lk * 8);
      acc[nt] = MFMA(af, bf, acc[nt]);
    }
  }
  #pragma unroll
  for (int nt = 0; nt < 4; ++nt) {
    int col = w * 64 + nt * 16 + lr;
    float bb = lin_b[col];
    #pragma unroll
    for (int e = 0; e < 4; ++e) {
      int row = lk * 4 + e;
      hidL[row * 260 + col] = fmaxf(acc[nt][e] + bb, 0.f);
    }
  }
  __syncthreads();
  if (tid < 64) {
    int row = tid >> 2, oc = tid & 3;
    float s = crit_b[oc];
    for (int k = 0; k < 256; ++k) s += hidL[row * 260 + k] * cw[oc * 256 + k];
    out[(m0 + row) * 4 + oc] = s;
  }
}

extern "C" void kernel_launch(void* const* d_in, const int* in_sizes, int n_in,
                              void* d_out, int out_size, void* d_ws, size_t ws_size,
                              hipStream_t stream) {
  const float* x    = (const float*)d_in[0];
  const int*   inst = (const int*)  d_in[1];
  const int*   stp  = (const int*)  d_in[2];
  const float* w1   = (const float*)d_in[3];
  const float* b1   = (const float*)d_in[4];
  const float* w2   = (const float*)d_in[5];
  const float* b2   = (const float*)d_in[6];
  const float* w3   = (const float*)d_in[7];
  const float* b3   = (const float*)d_in[8];
  const float* emb  = (const float*)d_in[9];
  const float* wih  = (const float*)d_in[10];
  const float* whh  = (const float*)d_in[11];
  const float* bih  = (const float*)d_in[12];
  const float* bhh  = (const float*)d_in[13];
  const float* aw   = (const float*)d_in[14];
  const float* ab   = (const float*)d_in[15];
  const float* lw   = (const float*)d_in[16];
  const float* lb   = (const float*)d_in[17];
  const float* cwp  = (const float*)d_in[18];
  const float* cb   = (const float*)d_in[19];
  float* out = (float*)d_out;

  char* ws = (char*)d_ws;
  short* flat  = (short*)(ws + 0);          // 4096*2304*2 = 18874368
  float* attnv = (float*)(ws + 18874368);   // 4096*64*4   = 1048576
  short* w1p   = (short*)(ws + 19922944);   // 16384
  short* w2p   = (short*)(ws + 19939328);   // 65536
  short* w3p   = (short*)(ws + 20004864);   // 32768
  short* wihp  = (short*)(ws + 20037632);   // 49152
  short* whhp  = (short*)(ws + 20086784);   // 393216
  short* attnp = (short*)(ws + 20480000);   // 32768
  short* linp  = (short*)(ws + 20512768);   // 1179648 -> total 21692416 bytes

  k_prep<<<dim3(3456), dim3(256), 0, stream>>>(w1, w2, w3, wih, whh, aw, lw,
                                               w1p, w2p, w3p, wihp, whhp, attnp, linp);
  k_gru<<<dim3(128), dim3(512), 0, stream>>>(inst, emb, wihp, whhp, bih, bhh,
                                             attnp, ab, attnv);
  k_conv<<<dim3(4096), dim3(256), 0, stream>>>(x, w1p, b1, w2p, b2, w3p, b3,
                                               attnv, stp, flat);
  k_lin<<<dim3(256), dim3(256), 0, stream>>>(flat, linp, lb, cwp, cb, out);
}

// Round 2
// 174.255 us; speedup vs baseline: 2.2428x; 2.2428x over previous
//
#include <hip/hip_runtime.h>

using bf16x8 = __attribute__((ext_vector_type(8))) short;
using f32x4  = __attribute__((ext_vector_type(4))) float;

#define MFMA(a,b,c) __builtin_amdgcn_mfma_f32_16x16x32_bf16((a),(b),(c),0,0,0)

__device__ __forceinline__ short f2bf(float f) {
  unsigned u = __builtin_bit_cast(unsigned, f);
  u += 0x7FFFu + ((u >> 16) & 1u);   // RNE
  return (short)(u >> 16);
}
__device__ __forceinline__ float sigm(float x) { return 1.0f / (1.0f + __expf(-x)); }
__device__ __forceinline__ float tanh_(float x) { return 2.0f * sigm(2.0f * x) - 1.0f; }

__device__ __forceinline__ bf16x8 pack8(float4 a, float4 b) {
  bf16x8 r;
  r[0]=f2bf(a.x); r[1]=f2bf(a.y); r[2]=f2bf(a.z); r[3]=f2bf(a.w);
  r[4]=f2bf(b.x); r[5]=f2bf(b.y); r[6]=f2bf(b.z); r[7]=f2bf(b.w);
  return r;
}

// ---------------- prep: weights -> bf16, MFMA-fragment-tiled layouts ----------------
// whh2/wih2/attn2: element (row,k) -> [row>>4][k>>3][row&15][k&7] so a wave's
// fragment load (16 rows x 8 k) is 16B-per-lane contiguous (coalesced).
__global__ void k_prep(const float* __restrict__ w1, const float* __restrict__ w2,
                       const float* __restrict__ w3, const float* __restrict__ wih,
                       const float* __restrict__ whh, const float* __restrict__ aw,
                       const float* __restrict__ lw,
                       short* __restrict__ w1p, short* __restrict__ w2p, short* __restrict__ w3p,
                       short* __restrict__ wihp, short* __restrict__ whhp,
                       short* __restrict__ attnp, short* __restrict__ linp)
{
  int i = blockIdx.x * 256 + threadIdx.x;
  if (i < 8192) {                       // w1p [128][64], k=c*9+dy*3+dx, pad 36..63 = 0
    int o = i >> 6, k = i & 63;
    float v = 0.f;
    if (k < 36) { int c = k / 9, r9 = k % 9; v = w1[((o*4 + c)*3 + r9/3)*3 + (r9%3)]; }
    w1p[i] = f2bf(v); return;
  }
  i -= 8192;
  if (i < 32768) {                      // w2p [64][512], k=(dy*2+dx)*128+c
    int o = i >> 9, k = i & 511;
    int dydx = k >> 7, c = k & 127;
    w2p[i] = f2bf(w2[((o*128 + c)*2 + (dydx>>1))*2 + (dydx&1)]); return;
  }
  i -= 32768;
  if (i < 16384) {                      // w3p [64][256], k=(dy*2+dx)*64+c
    int o = i >> 8, k = i & 255;
    int dydx = k >> 6, c = k & 63;
    w3p[i] = f2bf(w3[((o*64 + c)*2 + (dydx>>1))*2 + (dydx&1)]); return;
  }
  i -= 16384;
  if (i < 24576) {                      // wih2: [rt][kc(0..3)][r16][k8]
    int k8 = i & 7, r16 = (i >> 3) & 15, kc = (i >> 7) & 3, rt = i >> 9;
    wihp[i] = f2bf(wih[(rt*16 + r16) * 32 + kc*8 + k8]); return;
  }
  i -= 24576;
  if (i < 196608) {                     // whh2: [rt(0..47)][kc(0..31)][r16][k8]
    int k8 = i & 7, r16 = (i >> 3) & 15, kc = (i >> 7) & 31, rt = i >> 12;
    whhp[i] = f2bf(whh[(rt*16 + r16) * 256 + kc*8 + k8]); return;
  }
  i -= 196608;
  if (i < 16384) {                      // attn2: [rt(0..3)][kc(0..31)][r16][k8]
    int k8 = i & 7, r16 = (i >> 3) & 15, kc = (i >> 7) & 31, rt = i >> 12;
    attnp[i] = f2bf(aw[(rt*16 + r16) * 256 + kc*8 + k8]); return;
  }
  i -= 16384;
  if (i < 589824) { linp[i] = f2bf(lw[i]); return; }
}

// ---------------- GRU: whh register-resident, 256 blocks x 8 waves, Btile=16 ----------------
__global__ __launch_bounds__(512, 2) void k_gru(
    const int* __restrict__ inst, const float* __restrict__ emb_w,
    const short* __restrict__ wih2, const short* __restrict__ whh2,
    const float* __restrict__ b_ih, const float* __restrict__ b_hh,
    const short* __restrict__ attn2, const float* __restrict__ attn_b,
    float* __restrict__ attn_out)
{
  __shared__ short hA[16 * 256];       // bf16 h double-buffer, XOR-swizzled (row 512B)
  __shared__ short hB[16 * 256];
  __shared__ short xfL[16 * 64 * 8];   // [t][lane][8]: per-step A-fragments (16KB)
  __shared__ short wihL[6 * 512 * 8];  // [nt][tid][8]  (48KB)
  __shared__ short wf7L[6 * 512 * 8];  // whh ks=7 fragments [nt][tid][8] (48KB)

  const int tid = threadIdx.x;
  const int w = tid >> 6, l = tid & 63, lr = l & 15, lk = l >> 4;
  const int b0 = blockIdx.x * 16;
  const f32x4 z4 = {0.f, 0.f, 0.f, 0.f};

  // nt 0..1 = r, 2..3 = z, 4..5 = n ; wave w owns cols [32w,32w+32) of each gate
  int rtile[6], rowW[6];
  #pragma unroll
  for (int nt = 0; nt < 6; ++nt) {
    rtile[nt] = (nt >> 1) * 16 + w * 2 + (nt & 1);
    rowW[nt]  = rtile[nt] * 16 + lr;
  }

  // -------- preload whh fragments: ks 0..6 in VGPRs, ks 7 in LDS --------
  bf16x8 wf[6][7];
  #pragma unroll
  for (int nt = 0; nt < 6; ++nt) {
    #pragma unroll
    for (int ks = 0; ks < 7; ++ks)
      wf[nt][ks] = *(const bf16x8*)(whh2 + ((rtile[nt]*32 + ks*4 + lk)*16 + lr)*8);
    *(bf16x8*)(wf7L + (nt*512 + tid)*8) =
        *(const bf16x8*)(whh2 + ((rtile[nt]*32 + 28 + lk)*16 + lr)*8);
    *(bf16x8*)(wihL + (nt*512 + tid)*8) =
        *(const bf16x8*)(wih2 + ((rtile[nt]*4 + lk)*16 + lr)*8);
  }

  float biasRZ[4], bihN[2], bhhN[2];
  #pragma unroll
  for (int nt = 0; nt < 4; ++nt) biasRZ[nt] = b_ih[rowW[nt]] + b_hh[rowW[nt]];
  #pragma unroll
  for (int s = 0; s < 2; ++s) { bihN[s] = b_ih[rowW[4+s]]; bhhN[s] = b_hh[rowW[4+s]]; }

  // -------- precompute all 16 steps' x-fragments into LDS --------
  #pragma unroll
  for (int f = tid; f < 1024; f += 512) {
    int t = f >> 6, ll = f & 63, llr = ll & 15, llk = ll >> 4;
    int id = inst[(b0 + llr) * 16 + t];
    const float* ep = emb_w + id * 32 + llk * 8;
    *(bf16x8*)(xfL + f * 8) = pack8(*(const float4*)(ep), *(const float4*)(ep + 4));
  }

  for (int i = tid; i < 4096; i += 512) hA[i] = 0;

  float hOld[2][4];
  #pragma unroll
  for (int s = 0; s < 2; ++s)
    #pragma unroll
    for (int e = 0; e < 4; ++e) hOld[s][e] = 0.f;

  __syncthreads();

  #pragma unroll 2
  for (int t = 0; t < 16; ++t) {
    const short* hr = (t & 1) ? hB : hA;
    short*       hw = (t & 1) ? hA : hB;

    bf16x8 xf = *(const bf16x8*)(xfL + (t * 64 + l) * 8);
    f32x4 acc[6], gin[2];
    #pragma unroll
    for (int nt = 0; nt < 4; ++nt)
      acc[nt] = MFMA(xf, *(const bf16x8*)(wihL + (nt*512 + tid)*8), z4);
    #pragma unroll
    for (int s = 0; s < 2; ++s)
      gin[s] = MFMA(xf, *(const bf16x8*)(wihL + ((4+s)*512 + tid)*8), z4);
    acc[4] = z4; acc[5] = z4;

    #pragma unroll
    for (int ks = 0; ks < 7; ++ks) {
      int byte = (lr * 512 + ks * 64 + lk * 16) ^ ((lr & 7) << 4);
      bf16x8 hf = *(const bf16x8*)((const char*)hr + byte);
      #pragma unroll
      for (int nt = 0; nt < 6; ++nt) acc[nt] = MFMA(hf, wf[nt][ks], acc[nt]);
    }
    {   // ks = 7 from LDS stash
      int byte = (lr * 512 + 7 * 64 + lk * 16) ^ ((lr & 7) << 4);
      bf16x8 hf = *(const bf16x8*)((const char*)hr + byte);
      #pragma unroll
      for (int nt = 0; nt < 6; ++nt) {
        bf16x8 bw = *(const bf16x8*)(wf7L + (nt*512 + tid)*8);
        acc[nt] = MFMA(hf, bw, acc[nt]);
      }
    }

    #pragma unroll
    for (int s = 0; s < 2; ++s)
      #pragma unroll
      for (int e = 0; e < 4; ++e) {
        float r  = sigm(acc[s][e]     + biasRZ[s]);
        float zz = sigm(acc[2 + s][e] + biasRZ[2 + s]);
        float nn = tanh_(gin[s][e] + bihN[s] + r * (acc[4 + s][e] + bhhN[s]));
        float hn = (1.0f - zz) * nn + zz * hOld[s][e];
        hOld[s][e] = hn;
        int row = lk * 4 + e;               // D layout: row=(lane>>4)*4+reg (sample)
        int col = w * 32 + s * 16 + lr;     // D layout: col=lane&15 (hidden)
        int byte = (row * 512 + col * 2) ^ ((row & 7) << 4);
        *(short*)((char*)hw + byte) = f2bf(hn);
      }
    __syncthreads();   // dbuf: one barrier per step
  }

  // attn = sigmoid(h @ attn_w^T + attn_b); final h is in hA (t=15 wrote hA)
  if (w < 4) {
    f32x4 acc = z4;
    #pragma unroll
    for (int ks = 0; ks < 8; ++ks) {
      int byte = (lr * 512 + ks * 64 + lk * 16) ^ ((lr & 7) << 4);
      bf16x8 hf = *(const bf16x8*)((const char*)hA + byte);
      bf16x8 bw = *(const bf16x8*)(attn2 + ((w*32 + ks*4 + lk)*16 + lr)*8);
      acc = MFMA(hf, bw, acc);
    }
    float bb = attn_b[w * 16 + lr];
    #pragma unroll
    for (int e = 0; e < 4; ++e) {
      int row = lk * 4 + e;
      attn_out[(b0 + row) * 64 + w * 16 + lr] = sigm(acc[e] + bb);
    }
  }
}

// ---------------- fused conv1+conv2+conv3 + gating + PE -> flat bf16 ----------------
// 1 sample per block, 256 thr (4 waves).
__global__ __launch_bounds__(256, 4) void k_conv(
    const float* __restrict__ x,
    const short* __restrict__ w1p, const float* __restrict__ b1,
    const short* __restrict__ w2p, const float* __restrict__ b2,
    const short* __restrict__ w3p, const float* __restrict__ b3,
    const float* __restrict__ attn, const int* __restrict__ steps,
    short* __restrict__ flat)
{
  __shared__ float xs[400];
  __shared__ short A1[64 * 64];    // im2col conv1, K padded to 64, swizzled (row 128B)
  __shared__ short a1[64 * 128];   // conv1 out NHWC bf16, swizzled (row 256B)
  __shared__ short a2[49 * 64];    // conv2 out NHWC bf16, swizzled (row 128B)
  __shared__ short fst[2304];      // flat staging

  const int tid = threadIdx.x;
  const int w = tid >> 6, l = tid & 63, lr = l & 15, lk = l >> 4;
  const int b = blockIdx.x;
  const f32x4 z4 = {0.f, 0.f, 0.f, 0.f};

  for (int i = tid; i < 400; i += 256) xs[i] = x[b * 400 + i];
  __syncthreads();

  for (int i = tid; i < 4096; i += 256) {     // build im2col A1
    int p = i >> 6, k = i & 63;
    float v = 0.f;
    if (k < 36) {
      int c = k / 9, r9 = k % 9;
      v = xs[c * 100 + ((p >> 3) + r9 / 3) * 10 + (p & 7) + (r9 % 3)];
    }
    int byte = (p * 128 + k * 2) ^ ((p & 7) << 4);
    *(short*)((char*)A1 + byte) = f2bf(v);
  }
  __syncthreads();

  // conv1: wave w -> oc tiles {2w,2w+1} (base w*32); M=64 pixels, K=64(pad)
  f32x4 acc1[4][2];
  #pragma unroll
  for (int m = 0; m < 4; ++m) { acc1[m][0] = z4; acc1[m][1] = z4; }
  {
    bf16x8 wf[2][2];
    #pragma unroll
    for (int n = 0; n < 2; ++n)
      #pragma unroll
      for (int ks = 0; ks < 2; ++ks)
        wf[n][ks] = *(const bf16x8*)(w1p + (w * 32 + n * 16 + lr) * 64 + ks * 32 + lk * 8);
    #pragma unroll
    for (int ks = 0; ks < 2; ++ks)
      #pragma unroll
      for (int m = 0; m < 4; ++m) {
        int row = m * 16 + lr;
        int byte = (row * 128 + ks * 64 + lk * 16) ^ ((row & 7) << 4);
        bf16x8 af = *(const bf16x8*)((const char*)A1 + byte);
        acc1[m][0] = MFMA(af, wf[0][ks], acc1[m][0]);
        acc1[m][1] = MFMA(af, wf[1][ks], acc1[m][1]);
      }
  }
  #pragma unroll
  for (int m = 0; m < 4; ++m)
    #pragma unroll
    for (int n = 0; n < 2; ++n) {
      int oc = w * 32 + n * 16 + lr;
      float bb = b1[oc];
      #pragma unroll
      for (int e = 0; e < 4; ++e) {
        int p = m * 16 + lk * 4 + e;
        float v = fmaxf(acc1[m][n][e] + bb, 0.f);
        int byte = (p * 256 + oc * 2) ^ ((p & 7) << 4);
        *(short*)((char*)a1 + byte) = f2bf(v);
      }
    }
  __syncthreads();

  // conv2: wave w -> oc tile w*16; M=49(pad 64), K=512, A read straight from a1
  f32x4 acc2[4];
  #pragma unroll
  for (int m = 0; m < 4; ++m) acc2[m] = z4;
  {
    int base2[4];
    #pragma unroll
    for (int m = 0; m < 4; ++m) {
      int p = m * 16 + lr; if (p > 48) p = 48;
      base2[m] = (p / 7) * 8 + p % 7;
    }
    const int off2[4] = {0, 1, 8, 9};
    #pragma unroll
    for (int ks = 0; ks < 16; ++ks) {
      bf16x8 bf = *(const bf16x8*)(w2p + (w * 16 + lr) * 512 + ks * 32 + lk * 8);
      int dydx = ks >> 2;
      int colb = (ks & 3) * 64 + lk * 16;
      #pragma unroll
      for (int m = 0; m < 4; ++m) {
        int row = base2[m] + off2[dydx];
        int byte = (row * 256 + colb) ^ ((row & 7) << 4);
        bf16x8 af = *(const bf16x8*)((const char*)a1 + byte);
        acc2[m] = MFMA(af, bf, acc2[m]);
      }
    }
  }
  {
    int oc = w * 16 + lr;
    float bb = b2[oc];
    #pragma unroll
    for (int m = 0; m < 4; ++m)
      #pragma unroll
      for (int e = 0; e < 4; ++e) {
        int p = m * 16 + lk * 4 + e;
        if (p < 49) {
          float v = fmaxf(acc2[m][e] + bb, 0.f);
          int byte = (p * 128 + oc * 2) ^ ((p & 7) << 4);
          *(short*)((char*)a2 + byte) = f2bf(v);
        }
      }
  }
  __syncthreads();

  // conv3: M=36(pad 48), K=256
  f32x4 acc3[3];
  #pragma unroll
  for (int m = 0; m < 3; ++m) acc3[m] = z4;
  {
    int base3[3];
    #pragma unroll
    for (int m = 0; m < 3; ++m) {
      int p = m * 16 + lr; if (p > 35) p = 35;
      base3[m] = (p / 6) * 7 + p % 6;
    }
    const int off3[4] = {0, 1, 7, 8};
    #pragma unroll
    for (int ks = 0; ks < 8; ++ks) {
      bf16x8 bf = *(const bf16x8*)(w3p + (w * 16 + lr) * 256 + ks * 32 + lk * 8);
      int dydx = ks >> 1;
      int colb = (ks & 1) * 64 + lk * 16;
      #pragma unroll
      for (int m = 0; m < 3; ++m) {
        int row = base3[m] + off3[dydx];
        int byte = (row * 128 + colb) ^ ((row & 7) << 4);
        bf16x8 af = *(const bf16x8*)((const char*)a2 + byte);
        acc3[m] = MFMA(af, bf, acc3[m]);
      }
    }
  }
  // epilogue: bias+relu, * attn[b][oc], + PE[steps[b]][oc*36+p], -> fst bf16
  {
    int oc = w * 16 + lr;
    float av = attn[b * 64 + oc];
    float bb = b3[oc];
    float sf = (float)steps[b];
    const float C = (float)(-2.0 * (9.210340371976184 / 2304.0));  // -2*ln(1e4)/2304
    #pragma unroll
    for (int m = 0; m < 3; ++m)
      #pragma unroll
      for (int e = 0; e < 4; ++e) {
        int p = m * 16 + lk * 4 + e;
        if (p < 36) {
          float v = fmaxf(acc3[m][e] + bb, 0.f) * av;
          int k = oc * 36 + p;
          float ang = sf * expf((float)(k >> 1) * C);
          float pe = (k & 1) ? cosf(ang) : sinf(ang);
          fst[k] = f2bf(v + pe);
        }
      }
  }
  __syncthreads();
  for (int i = tid; i < 288; i += 256)
    *(bf16x8*)(flat + b * 2304 + i * 8) = *(const bf16x8*)(fst + i * 8);
}

// ---------------- lin (M=4096,N=256,K=2304) + relu + critic ----------------
// 256 blocks (BM=16, BN=256 full), 256 thr (4 waves, wave w -> cols [64w,64w+64))
__global__ __launch_bounds__(256, 4) void k_lin(
    const short* __restrict__ flat, const short* __restrict__ linp,
    const float* __restrict__ lin_b, const float* __restrict__ crit_w,
    const float* __restrict__ crit_b, float* __restrict__ out)
{
  __shared__ float hidL[16 * 260];   // +4 pad: breaks 1KB-stride bank aliasing
  __shared__ float cw[1024];
  const int tid = threadIdx.x;
  const int w = tid >> 6, l = tid & 63, lr = l & 15, lk = l >> 4;
  const int m0 = blockIdx.x * 16;
  const f32x4 z4 = {0.f, 0.f, 0.f, 0.f};

  for (int i = tid; i < 1024; i += 256) cw[i] = crit_w[i];

  f32x4 acc[4];
  #pragma unroll
  for (int nt = 0; nt < 4; ++nt) acc[nt] = z4;

  #pragma unroll 2
  for (int ks = 0; ks < 72; ++ks) {
    bf16x8 af = *(const bf16x8*)(flat + (m0 + lr) * 2304 + ks * 32 + lk * 8);
    #pragma unroll
    for (int nt = 0; nt < 4; ++nt) {
      bf16x8 bf = *(const bf16x8*)(linp + (w * 64 + nt * 16 + lr) * 2304 + ks * 32 + lk * 8);
      acc[nt] = MFMA(af, bf, acc[nt]);
    }
  }
  #pragma unroll
  for (int nt = 0; nt < 4; ++nt) {
    int col = w * 64 + nt * 16 + lr;
    float bb = lin_b[col];
    #pragma unroll
    for (int e = 0; e < 4; ++e) {
      int row = lk * 4 + e;
      hidL[row * 260 + col] = fmaxf(acc[nt][e] + bb, 0.f);
    }
  }
  __syncthreads();
  if (tid < 64) {
    int row = tid >> 2, oc = tid & 3;
    float s = crit_b[oc];
    for (int k = 0; k < 256; ++k) s += hidL[row * 260 + k] * cw[oc * 256 + k];
    out[(m0 + row) * 4 + oc] = s;
  }
}

extern "C" void kernel_launch(void* const* d_in, const int* in_sizes, int n_in,
                              void* d_out, int out_size, void* d_ws, size_t ws_size,
                              hipStream_t stream) {
  const float* x    = (const float*)d_in[0];
  const int*   inst = (const int*)  d_in[1];
  const int*   stp  = (const int*)  d_in[2];
  const float* w1   = (const float*)d_in[3];
  const float* b1   = (const float*)d_in[4];
  const float* w2   = (const float*)d_in[5];
  const float* b2   = (const float*)d_in[6];
  const float* w3   = (const float*)d_in[7];
  const float* b3   = (const float*)d_in[8];
  const float* emb  = (const float*)d_in[9];
  const float* wih  = (const float*)d_in[10];
  const float* whh  = (const float*)d_in[11];
  const float* bih  = (const float*)d_in[12];
  const float* bhh  = (const float*)d_in[13];
  const float* aw   = (const float*)d_in[14];
  const float* ab   = (const float*)d_in[15];
  const float* lw   = (const float*)d_in[16];
  const float* lb   = (const float*)d_in[17];
  const float* cwp  = (const float*)d_in[18];
  const float* cb   = (const float*)d_in[19];
  float* out = (float*)d_out;

  char* ws = (char*)d_ws;
  short* flat  = (short*)(ws + 0);          // 4096*2304*2 = 18874368
  float* attnv = (float*)(ws + 18874368);   // 4096*64*4   = 1048576
  short* w1p   = (short*)(ws + 19922944);   // 16384
  short* w2p   = (short*)(ws + 19939328);   // 65536
  short* w3p   = (short*)(ws + 20004864);   // 32768
  short* wihp  = (short*)(ws + 20037632);   // 49152
  short* whhp  = (short*)(ws + 20086784);   // 393216
  short* attnp = (short*)(ws + 20480000);   // 32768
  short* linp  = (short*)(ws + 20512768);   // 1179648 -> total 21692416 bytes

  k_prep<<<dim3(3456), dim3(256), 0, stream>>>(w1, w2, w3, wih, whh, aw, lw,
                                               w1p, w2p, w3p, wihp, whhp, attnp, linp);
  k_gru<<<dim3(256), dim3(512), 0, stream>>>(inst, emb, wihp, whhp, bih, bhh,
                                             attnp, ab, attnv);
  k_conv<<<dim3(4096), dim3(256), 0, stream>>>(x, w1p, b1, w2p, b2, w3p, b3,
                                               attnv, stp, flat);
  k_lin<<<dim3(256), dim3(256), 0, stream>>>(flat, linp, lb, cwp, cb, out);
}